// Round 3
// baseline (24764.632 us; speedup 1.0000x reference)
//
#include <hip/hip_runtime.h>
#include <stdint.h>

typedef __bf16 bf16x8 __attribute__((ext_vector_type(8)));
typedef float  f32x4  __attribute__((ext_vector_type(4)));

static __device__ __forceinline__ unsigned short f2bf(float f) {
  unsigned int u = __float_as_uint(f);
  u = u + 0x7fffu + ((u >> 16) & 1u);
  return (unsigned short)(u >> 16);
}
static __device__ __forceinline__ float bf2f(unsigned short h) {
  return __uint_as_float(((unsigned int)h) << 16);
}
static __device__ __forceinline__ float sigm(float x) {
  return 1.f / (1.f + __expf(-x));
}
static __device__ __forceinline__ float tanh_f(float x) {
  float ax = fabsf(x);
  float e = __expf(-2.f * ax);
  float t = (1.f - e) / (1.f + e);
  return copysignf(t, x);
}

// ---------------- weight packing ----------------
// W4F bf16 fragment-major [T=200][kc=26][lane=64][8]:
//   tile T: tpair=T&1 (0:gates i,f ; 1:gates g,o), colOct=T>>1 (8 h2-cols)
//   unit(T, n=l16): gate=(tpair?2:0)+(n>>3), col=colOct*8+(n&7)
//   k = kc*32 + q*8 + j; K-layout: k<20 Wih4, 20..23 zero, 24..823 Whh4[k-24], 824.. zero
// W5 bf16 row-major [512 x 928]: k<800 Wih5 (h2), 800..927 Whh5 (h3)
// W1 f32 [240 x 192], W2 f32 [80 x 80], W3 f32 [80 x 40]
// b4[3200], b5[512], b1[240], b2[80], b3[80] (bih+bhh)
__global__ void kPrep(const float* __restrict__ w4i, const float* __restrict__ w4h,
                      const float* __restrict__ b4i, const float* __restrict__ b4h,
                      const float* __restrict__ w5i, const float* __restrict__ w5h,
                      const float* __restrict__ b5i, const float* __restrict__ b5h,
                      const float* __restrict__ w1i, const float* __restrict__ w1h,
                      const float* __restrict__ b1i, const float* __restrict__ b1h,
                      const float* __restrict__ w2i, const float* __restrict__ w2h,
                      const float* __restrict__ b2i, const float* __restrict__ b2h,
                      const float* __restrict__ w3i, const float* __restrict__ w3h,
                      const float* __restrict__ b3i, const float* __restrict__ b3h,
                      unsigned short* __restrict__ W4F, unsigned short* __restrict__ W5,
                      float* __restrict__ W1, float* __restrict__ W2, float* __restrict__ W3,
                      float* __restrict__ b4, float* __restrict__ b5,
                      float* __restrict__ b1, float* __restrict__ b2, float* __restrict__ b3) {
  int idx0 = blockIdx.x * blockDim.x + threadIdx.x;
  int stride = gridDim.x * blockDim.x;
  const int TOT = 3197328;
  for (int i = idx0; i < TOT; i += stride) {
    int i2 = i;
    if (i2 < 2662400) {  // W4F fragment-major
      int T = i2 / 13312;         // 26*512
      int r1 = i2 % 13312;
      int kc = r1 / 512;
      int e = r1 % 512;
      int lane = e >> 3, j = e & 7;
      int q = lane >> 4, l16 = lane & 15;
      int gate = ((T & 1) ? 2 : 0) + (l16 >> 3);
      int col = (T >> 1) * 8 + (l16 & 7);
      int wrow = gate * 800 + col;
      int k = kc * 32 + q * 8 + j;
      float v = (k < 20) ? w4i[wrow * 20 + k]
                         : ((k >= 24 && k < 824) ? w4h[wrow * 800 + (k - 24)] : 0.f);
      W4F[i2] = f2bf(v);
      continue;
    }
    i2 -= 2662400;
    if (i2 < 475136) {  // W5 row-major
      int n = i2 / 928, k = i2 % 928;
      float v = (k < 800) ? w5i[n * 800 + k] : w5h[n * 128 + (k - 800)];
      W5[i2] = f2bf(v);
      continue;
    }
    i2 -= 475136;
    if (i2 < 46080) {
      int n = i2 / 192, k = i2 % 192;
      W1[i2] = (k < 128) ? w1i[n * 128 + k] : ((k < 188) ? w1h[n * 60 + (k - 128)] : 0.f);
      continue;
    }
    i2 -= 46080;
    if (i2 < 6400) {
      int n = i2 / 80, k = i2 % 80;
      W2[i2] = (k < 60) ? w2i[n * 60 + k] : w2h[n * 20 + (k - 60)];
      continue;
    }
    i2 -= 6400;
    if (i2 < 3200) {
      int n = i2 / 40, k = i2 % 40;
      W3[i2] = (k < 20) ? w3i[n * 20 + k] : w3h[n * 20 + (k - 20)];
      continue;
    }
    i2 -= 3200;
    if (i2 < 3200) { b4[i2] = b4i[i2] + b4h[i2]; continue; }
    i2 -= 3200;
    if (i2 < 512) { b5[i2] = b5i[i2] + b5h[i2]; continue; }
    i2 -= 512;
    if (i2 < 240) { b1[i2] = b1i[i2] + b1h[i2]; continue; }
    i2 -= 240;
    if (i2 < 80) { b2[i2] = b2i[i2] + b2h[i2]; continue; }
    i2 -= 80;
    b3[i2] = b3i[i2] + b3h[i2];
  }
}

// zero packed activation buffers (both parities) + barrier/flag words
__global__ void kZero(unsigned int* __restrict__ pk, unsigned int* __restrict__ bf) {
  int idx = blockIdx.x * blockDim.x + threadIdx.x;
  int stride = gridDim.x * blockDim.x;
  for (int i = idx; i < 974848; i += stride) pk[i] = 0u;
  if (idx < 128) bf[idx] = 0u;
}

// ---------------- encoder: fc1 + fc21 fused, 4 batch rows / block ----------
__global__ __launch_bounds__(256, 2)
void kEnc(const float* __restrict__ x,
          const float* __restrict__ W1, const float* __restrict__ b1,
          const float* __restrict__ W2, const float* __restrict__ b2,
          const float* __restrict__ idW, const float* __restrict__ idb,
          float* __restrict__ hl30, float* __restrict__ cl30,
          float* __restrict__ out0, float* __restrict__ muOut) {
  __shared__ float xb[512];
  __shared__ float hb[240], cbb[240], h1b[240];
  __shared__ float h21[80], c21[80];
  __shared__ float g1[960], g2[320];
  const int tid = threadIdx.x;
  const int rowbase = blockIdx.x * 4;
  if (tid < 240) { hb[tid] = 0.f; cbb[tid] = 0.f; h1b[tid] = 0.f; }
  if (tid < 80) { h21[tid] = 0.f; c21[tid] = 0.f; }
  __syncthreads();
  for (int t = 0; t < 256; ++t) {
    const float* xs = x + ((size_t)t * 1024 + rowbase) * 128;
    xb[tid] = xs[tid];
    xb[tid + 256] = xs[tid + 256];
    __syncthreads();
    if (tid < 240) {
      const float* wr = W1 + tid * 192;
      float s0 = b1[tid], s1 = s0, s2 = s0, s3 = s0;
      for (int k = 0; k < 128; ++k) {
        float w = wr[k];
        s0 += w * xb[k]; s1 += w * xb[128 + k]; s2 += w * xb[256 + k]; s3 += w * xb[384 + k];
      }
      for (int k = 0; k < 60; ++k) {
        float w = wr[128 + k];
        s0 += w * hb[k]; s1 += w * hb[60 + k]; s2 += w * hb[120 + k]; s3 += w * hb[180 + k];
      }
      g1[tid] = s0; g1[240 + tid] = s1; g1[480 + tid] = s2; g1[720 + tid] = s3;
    }
    __syncthreads();
    if (tid < 240) {
      int b = tid / 60, j = tid % 60;
      const float* g = g1 + b * 240;
      float iv = sigm(g[j]), fv = sigm(g[60 + j]), gv = tanh_f(g[120 + j]), ov = sigm(g[180 + j]);
      float c = fv * cbb[b * 60 + j] + iv * gv;
      cbb[b * 60 + j] = c;
      float h = ov * tanh_f(c);
      hb[b * 60 + j] = h;
      h1b[b * 60 + j] = fmaxf(h, 0.f);
    }
    __syncthreads();
    if (tid < 80) {
      const float* wr = W2 + tid * 80;
      float s0 = b2[tid], s1 = s0, s2 = s0, s3 = s0;
      for (int k = 0; k < 60; ++k) {
        float w = wr[k];
        s0 += w * h1b[k]; s1 += w * h1b[60 + k]; s2 += w * h1b[120 + k]; s3 += w * h1b[180 + k];
      }
      for (int k = 0; k < 20; ++k) {
        float w = wr[60 + k];
        s0 += w * h21[k]; s1 += w * h21[20 + k]; s2 += w * h21[40 + k]; s3 += w * h21[60 + k];
      }
      g2[tid] = s0; g2[80 + tid] = s1; g2[160 + tid] = s2; g2[240 + tid] = s3;
    }
    __syncthreads();
    if (tid < 80) {
      int b = tid / 20, j = tid % 20;
      const float* g = g2 + b * 80;
      float iv = sigm(g[j]), fv = sigm(g[20 + j]), gv = tanh_f(g[40 + j]), ov = sigm(g[60 + j]);
      float c = fv * c21[b * 20 + j] + iv * gv;
      c21[b * 20 + j] = c;
      h21[b * 20 + j] = ov * tanh_f(c);
    }
    __syncthreads();
  }
  if (tid < 80) {
    int b = tid / 20, j = tid % 20;
    int gb = rowbase + b;
    float mu = h21[b * 20 + j];
    muOut[(size_t)gb * 20 + j] = mu;
    hl30[gb * 20 + j] = mu;
    cl30[gb * 20 + j] = c21[b * 20 + j];
    float s = idb[j];
    for (int k = 0; k < 20; ++k) s += h21[b * 20 + k] * idW[j * 20 + k];
    out0[gb * 20 + j] = s;
  }
}

// ---------------- persistent decoder (normal launch, 256 blocks = 1/CU) ----
// Packed activation buffer (x2 parity): [1024][952] bf16:
//   col 0..19  = h_l3(t)   (l3 blocks, phase A, into READ buf)
//   col 20..23 = zero pad
//   col 24..823= h2(t)     (l4 blocks, phase A, into WRITE buf)
//   col 824..951= h3(t)    (l5 role,  phase B, into WRITE buf)
// l4 A = cols 0..831 of READ buf (units 824..831 have zero weights).
// l5 A = cols 24..951: kc 0..24 from WRITE buf (h2(t)), kc 25..28 from READ buf (h3(t-1)).
#define NBLK 256

static __device__ __forceinline__ void gbar(unsigned int* bar, unsigned int target) {
  __syncthreads();
  if (threadIdx.x == 0) {
    __hip_atomic_fetch_add(bar, 1u, __ATOMIC_RELEASE, __HIP_MEMORY_SCOPE_AGENT);
    while (__hip_atomic_load(bar, __ATOMIC_RELAXED, __HIP_MEMORY_SCOPE_AGENT) < target)
      __builtin_amdgcn_s_sleep(1);
    (void)__hip_atomic_load(bar, __ATOMIC_ACQUIRE, __HIP_MEMORY_SCOPE_AGENT);
  }
  __syncthreads();
}

__global__ __launch_bounds__(256, 1)
void kDec(const unsigned short* __restrict__ W4F, const float* __restrict__ b4,
          const unsigned short* __restrict__ W5, const float* __restrict__ b5,
          const float* __restrict__ W3g, const float* __restrict__ b3g,
          const float* __restrict__ dWg, const float* __restrict__ dbg,
          const float* __restrict__ out0, const float* __restrict__ hl3g,
          const float* __restrict__ cl3g,
          unsigned short* __restrict__ pk0, unsigned short* __restrict__ pk1,
          float* __restrict__ dout, unsigned int* __restrict__ barflag) {
  // LDS: [0, 49552) l3 scalar state (l3 blocks only)
  //      [49552, 59792) phase-B K-split reduction buffer (all blocks)
  __shared__ __align__(16) char smem[59792];
  unsigned int* bar = barflag;
  unsigned int* flag = barflag + 64;

  const int tid = threadIdx.x;
  const int b = blockIdx.x;
  const int lane = tid & 63, wv = tid >> 6;
  const int q = lane >> 4, l16 = lane & 15;

  float* red = (float*)(smem + 49552);
  float* S = (float*)smem;
  float* lsHl = S;                                   // 640
  float* lsCl = S + 640;                             // 640
  float* lsOut = S + 1280;                           // 640
  float* lsG = S + 1920;                             // 2560
  float* lsW3 = S + 4480;                            // 3200
  float* lsb3 = S + 7680;                            // 80
  float* lsdW = S + 7760;                            // 2560
  float* lsdb = S + 10320;                           // 20
  unsigned short* lsH3 = (unsigned short*)(S + 10340);  // 32x128 bf16

  const bool isL4 = (b < 200);
  const bool isL3 = (b >= 200) && (b < 232);

  // ---- l4 one-time setup: B-fragments of W4 into registers ----
  const int cg = b % 25, rg = b / 25;   // col-group (128 units), row-group (128 rows)
  const int colOct = cg * 4 + wv;
  const int col4 = colOct * 8 + (l16 & 7);
  const bool lo = (l16 & 8) == 0;
  bf16x8 B40[26], B41[26];
  float bb0 = 0.f, bb1 = 0.f;
  float c2reg[32];
  if (isL4) {
    const int T0 = cg * 8 + wv * 2;
    const unsigned short* p0 = W4F + (size_t)T0 * 13312 + lane * 8;
    const unsigned short* p1 = W4F + (size_t)(T0 + 1) * 13312 + lane * 8;
#pragma unroll
    for (int kc = 0; kc < 26; ++kc) {
      B40[kc] = *(const bf16x8*)(p0 + kc * 512);
      B41[kc] = *(const bf16x8*)(p1 + kc * 512);
    }
    const int g0 = (l16 >> 3), g1 = 2 + (l16 >> 3);
    bb0 = b4[g0 * 800 + col4];
    bb1 = b4[g1 * 800 + col4];
#pragma unroll
    for (int i = 0; i < 32; ++i) c2reg[i] = 0.f;
  }
  // ---- l3 one-time setup ----
  const int rb3 = (b - 200) * 32;
  if (isL3) {
    for (int i = tid; i < 3200; i += 256) lsW3[i] = W3g[i];
    for (int i = tid; i < 2560; i += 256) lsdW[i] = dWg[i];
    if (tid < 80) lsb3[tid] = b3g[tid];
    if (tid < 20) lsdb[tid] = dbg[tid];
    for (int i = tid; i < 640; i += 256) {
      lsHl[i] = hl3g[rb3 * 20 + i];
      lsCl[i] = cl3g[rb3 * 20 + i];
    }
  }
  // ---- l5 role (all blocks) ----
  const int ry = b >> 3, jx = b & 7;
  const int rowf = wv & 1, kh = wv >> 1;
  const int rb5 = ry * 32 + rowf * 16;
  const int u5 = jx * 16 + l16;
  float c3reg[4] = {0.f, 0.f, 0.f, 0.f};
  const float bi5 = b5[u5], bf5 = b5[128 + u5], bg5 = b5[256 + u5], bo5 = b5[384 + u5];
  const size_t Aoff5 = (size_t)(rb5 + l16) * 952 + 24 + q * 8;
  const unsigned short* Brow5[4];
#pragma unroll
  for (int g = 0; g < 4; ++g) Brow5[g] = W5 + (size_t)(g * 128 + u5) * 928 + q * 8;

  __syncthreads();

  unsigned int barTarget = 0;
  for (int t = 0; t < 256; ++t) {
    unsigned short* pkR = (t & 1) ? pk1 : pk0;
    unsigned short* pkW = (t & 1) ? pk0 : pk1;
    // ================= PHASE A: l3 (scalar) + l4 (MFMA, B in regs) ========
    if (isL3) {
      if (t == 0) {
        for (int i = tid; i < 640; i += 256) lsOut[i] = out0[rb3 * 20 + i];
      } else {
        for (int i = tid; i < 512; i += 256) {
          int r = i >> 4, s = i & 15;
          *(uint4*)(lsH3 + r * 128 + s * 8) =
              *(const uint4*)(pkR + (size_t)(rb3 + r) * 952 + 824 + s * 8);
        }
        __syncthreads();
        for (int i = tid; i < 640; i += 256) {
          int r = i / 20, k = i - r * 20;
          const unsigned short* hr = lsH3 + r * 128;
          const float* wr = lsdW + k * 128;
          float s = lsdb[k];
          for (int j = 0; j < 128; ++j) s += bf2f(hr[j]) * wr[j];
          lsOut[i] = s;
        }
      }
      __syncthreads();
      for (int i = tid; i < 2560; i += 256) {
        int r = i / 80, n = i - r * 80;
        const float* wr = lsW3 + n * 40;
        const float* ob = lsOut + r * 20;
        const float* hp = lsHl + r * 20;
        float s = lsb3[n];
#pragma unroll
        for (int k = 0; k < 20; ++k) s += ob[k] * wr[k];
#pragma unroll
        for (int k = 0; k < 20; ++k) s += hp[k] * wr[20 + k];
        lsG[i] = s;
      }
      __syncthreads();
      for (int i = tid; i < 640; i += 256) {
        int r = i / 20, j = i - r * 20;
        const float* g = lsG + r * 80;
        float cv = sigm(g[20 + j]) * lsCl[i] + sigm(g[j]) * tanh_f(g[40 + j]);
        float hv = sigm(g[60 + j]) * tanh_f(cv);
        lsCl[i] = cv;
        lsHl[i] = hv;
        pkR[(size_t)(rb3 + r) * 952 + j] = f2bf(hv);  // h(t) into READ buffer
      }
      __syncthreads();  // drains stores before flag release
      if (tid == 0)
        __hip_atomic_fetch_add(flag, 1u, __ATOMIC_RELEASE, __HIP_MEMORY_SCOPE_AGENT);
    } else if (isL4) {
      f32x4 acc[8][2];
#pragma unroll
      for (int mi = 0; mi < 8; ++mi) {
        acc[mi][0] = (f32x4){0.f, 0.f, 0.f, 0.f};
        acc[mi][1] = (f32x4){0.f, 0.f, 0.f, 0.f};
      }
      const unsigned short* Ab = pkR + (size_t)(rg * 128 + l16) * 952 + q * 8;
#pragma unroll
      for (int kc = 1; kc < 26; ++kc) {
        bf16x8 a[8];
#pragma unroll
        for (int mi = 0; mi < 8; ++mi)
          a[mi] = *(const bf16x8*)(Ab + (size_t)mi * 15232 + kc * 32);
#pragma unroll
        for (int mi = 0; mi < 8; ++mi) {
          acc[mi][0] = __builtin_amdgcn_mfma_f32_16x16x32_bf16(a[mi], B40[kc], acc[mi][0], 0, 0, 0);
          acc[mi][1] = __builtin_amdgcn_mfma_f32_16x16x32_bf16(a[mi], B41[kc], acc[mi][1], 0, 0, 0);
        }
      }
      // wait for l3's h(t) (cols 0..19), then deferred K-chunk 0
      if (tid == 0) {
        while (__hip_atomic_load(flag, __ATOMIC_RELAXED, __HIP_MEMORY_SCOPE_AGENT) < 32u * (t + 1))
          __builtin_amdgcn_s_sleep(1);
        (void)__hip_atomic_load(flag, __ATOMIC_ACQUIRE, __HIP_MEMORY_SCOPE_AGENT);
      }
      __syncthreads();
#pragma unroll
      for (int mi = 0; mi < 8; ++mi) {
        bf16x8 a0 = *(const bf16x8*)(Ab + (size_t)mi * 15232);
        acc[mi][0] = __builtin_amdgcn_mfma_f32_16x16x32_bf16(a0, B40[0], acc[mi][0], 0, 0, 0);
        acc[mi][1] = __builtin_amdgcn_mfma_f32_16x16x32_bf16(a0, B41[0], acc[mi][1], 0, 0, 0);
      }
      // epilogue: gather i/f/g/o per lane via xor-8 shuffle, update cell, store h2
#pragma unroll
      for (int mi = 0; mi < 8; ++mi) {
#pragma unroll
        for (int r = 0; r < 4; ++r) {
          float v0 = acc[mi][0][r] + bb0;
          float v1 = acc[mi][1][r] + bb1;
          float p0 = __shfl_xor(v0, 8);
          float p1 = __shfl_xor(v1, 8);
          float iv = sigm(lo ? v0 : p0);
          float fv = sigm(lo ? p0 : v0);
          float gv = tanh_f(lo ? v1 : p1);
          float ov = sigm(lo ? p1 : v1);
          float cv = fv * c2reg[mi * 4 + r] + iv * gv;
          c2reg[mi * 4 + r] = cv;
          float hv = ov * tanh_f(cv);
          if (lo)
            pkW[(size_t)(rg * 128 + mi * 16 + q * 4 + r) * 952 + 24 + col4] = f2bf(hv);
        }
      }
    }
    barTarget += NBLK;
    gbar(bar, barTarget);
    // ================= PHASE B: l5 (MFMA, all blocks, K-split wave pairs) ==
    {
      f32x4 a5[4];
#pragma unroll
      for (int g = 0; g < 4; ++g) a5[g] = (f32x4){0.f, 0.f, 0.f, 0.f};
      const int kcB = kh ? 15 : 0, kcE = kh ? 25 : 15;
      for (int kc = kcB; kc < kcE; ++kc) {
        bf16x8 av = *(const bf16x8*)(pkW + Aoff5 + kc * 32);
#pragma unroll
        for (int g = 0; g < 4; ++g) {
          bf16x8 bv = *(const bf16x8*)(Brow5[g] + kc * 32);
          a5[g] = __builtin_amdgcn_mfma_f32_16x16x32_bf16(av, bv, a5[g], 0, 0, 0);
        }
      }
      if (kh) {
        for (int kc = 25; kc < 29; ++kc) {  // h3(t-1) region lives in READ buffer
          bf16x8 av = *(const bf16x8*)(pkR + Aoff5 + kc * 32);
#pragma unroll
          for (int g = 0; g < 4; ++g) {
            bf16x8 bv = *(const bf16x8*)(Brow5[g] + kc * 32);
            a5[g] = __builtin_amdgcn_mfma_f32_16x16x32_bf16(av, bv, a5[g], 0, 0, 0);
          }
        }
        float* myred = red + (rowf * 64 + lane) * 20;
#pragma unroll
        for (int g = 0; g < 4; ++g) *(f32x4*)(myred + g * 4) = a5[g];
      }
      __syncthreads();
      if (!kh) {
        const float* myred = red + (rowf * 64 + lane) * 20;
#pragma unroll
        for (int g = 0; g < 4; ++g) a5[g] += *(const f32x4*)(myred + g * 4);
#pragma unroll
        for (int r = 0; r < 4; ++r) {
          int row = rb5 + q * 4 + r;
          float iv = sigm(a5[0][r] + bi5);
          float fv = sigm(a5[1][r] + bf5);
          float gv = tanh_f(a5[2][r] + bg5);
          float ov = sigm(a5[3][r] + bo5);
          float cv = fv * c3reg[r] + iv * gv;
          c3reg[r] = cv;
          float hv = ov * tanh_f(cv);
          dout[(size_t)t * 131072 + (size_t)row * 128 + u5] = hv;
          pkW[(size_t)row * 952 + 824 + u5] = f2bf(hv);
        }
      }
    }
    barTarget += NBLK;
    if (t < 255) gbar(bar, barTarget);
  }
}

extern "C" void kernel_launch(void* const* d_in, const int* in_sizes, int n_in,
                              void* d_out, int out_size, void* d_ws, size_t ws_size,
                              hipStream_t stream) {
  (void)in_sizes; (void)n_in; (void)out_size; (void)ws_size;
  const float* x   = (const float*)d_in[0];
  const float* w1i = (const float*)d_in[1];
  const float* w1h = (const float*)d_in[2];
  const float* b1i = (const float*)d_in[3];
  const float* b1h = (const float*)d_in[4];
  const float* w2i = (const float*)d_in[5];
  const float* w2h = (const float*)d_in[6];
  const float* b2i = (const float*)d_in[7];
  const float* b2h = (const float*)d_in[8];
  const float* w3i = (const float*)d_in[9];
  const float* w3h = (const float*)d_in[10];
  const float* b3i = (const float*)d_in[11];
  const float* b3h = (const float*)d_in[12];
  const float* w4i = (const float*)d_in[13];
  const float* w4h = (const float*)d_in[14];
  const float* b4i = (const float*)d_in[15];
  const float* b4h = (const float*)d_in[16];
  const float* w5i = (const float*)d_in[17];
  const float* w5h = (const float*)d_in[18];
  const float* b5i = (const float*)d_in[19];
  const float* b5h = (const float*)d_in[20];
  const float* idW = (const float*)d_in[21];
  const float* idb = (const float*)d_in[22];
  const float* dWp = (const float*)d_in[23];
  const float* dbp = (const float*)d_in[24];
  float* out = (float*)d_out;

  char* ws = (char*)d_ws;
  size_t off = 0;
  auto alloc = [&](size_t bytes) -> void* {
    void* p = ws + off;
    off = (off + bytes + 255) & ~(size_t)255;
    return p;
  };
  unsigned short* W4F = (unsigned short*)alloc(3200 * 832 * 2);
  unsigned short* W5 = (unsigned short*)alloc(512 * 928 * 2);
  float* W1 = (float*)alloc(240 * 192 * 4);
  float* W2 = (float*)alloc(80 * 80 * 4);
  float* W3 = (float*)alloc(80 * 40 * 4);
  float* b4 = (float*)alloc(3200 * 4);
  float* b5 = (float*)alloc(512 * 4);
  float* b1 = (float*)alloc(240 * 4);
  float* b2 = (float*)alloc(80 * 4);
  float* b3 = (float*)alloc(80 * 4);
  unsigned short* pk0 = (unsigned short*)alloc((size_t)1024 * 952 * 2);
  unsigned short* pk1 = (unsigned short*)alloc((size_t)1024 * 952 * 2);
  float* hl3 = (float*)alloc(1024 * 20 * 4);
  float* cl3 = (float*)alloc(1024 * 20 * 4);
  float* out0 = (float*)alloc(1024 * 20 * 4);
  unsigned int* barflag = (unsigned int*)alloc(512);

  kPrep<<<dim3(4096), dim3(256), 0, stream>>>(
      w4i, w4h, b4i, b4h, w5i, w5h, b5i, b5h, w1i, w1h, b1i, b1h,
      w2i, w2h, b2i, b2h, w3i, w3h, b3i, b3h,
      W4F, W5, W1, W2, W3, b4, b5, b1, b2, b3);
  kZero<<<dim3(1024), dim3(256), 0, stream>>>((unsigned int*)pk0, barflag);
  kEnc<<<dim3(256), dim3(256), 0, stream>>>(x, W1, b1, W2, b2, idW, idb,
                                            hl3, cl3, out0, out + 33554432);
  kDec<<<dim3(256), dim3(256), 0, stream>>>(W4F, b4, W5, b5, W3, b3, dWp, dbp,
                                            out0, hl3, cl3, pk0, pk1, out, barflag);
}